// Round 1
// baseline (6269.983 us; speedup 1.0000x reference)
//
#include <hip/hip_runtime.h>
#include <cstddef>

#define S_ 32
#define NM1 127
#define D_ 256
#define F_ 516
#define TRI_ 8128
#define G_ 768
#define M_ (S_ * NM1)   // 4064

typedef __bf16 v8bf __attribute__((ext_vector_type(8)));
typedef float v4f __attribute__((ext_vector_type(4)));

__device__ __forceinline__ unsigned short f2bf(float f) {
    unsigned int u = __float_as_uint(f);
    unsigned int r = (u + 0x7FFFu + ((u >> 16) & 1u)) >> 16;
    return (unsigned short)r;
}

__device__ __forceinline__ void store4bf(unsigned short* p, float4 v) {
    ushort4 q;
    q.x = f2bf(v.x); q.y = f2bf(v.y); q.z = f2bf(v.z); q.w = f2bf(v.w);
    *(ushort4*)p = q;
}

__device__ __forceinline__ float sigmoidf_(float x) { return 1.f / (1.f + __expf(-x)); }

// ---------------------------------------------------------------------------
// K1: c0 = MLPReadout([z;init]) through cc_*; also zero d_out. 1 block x 1024.
// ---------------------------------------------------------------------------
__global__ __launch_bounds__(1024) void c0_kernel(
    const float* __restrict__ z_ph, const float* __restrict__ init_ph,
    const float* __restrict__ W0, const float* __restrict__ b0,
    const float* __restrict__ W1, const float* __restrict__ b1,
    const float* __restrict__ W2, const float* __restrict__ b2,
    float* __restrict__ c0_out, float* __restrict__ out_zero)
{
    __shared__ float v[512];
    __shared__ float h0[256];
    __shared__ float h1[128];
    __shared__ float red[4][256];
    __shared__ float red1[8][128];
    const int t = threadIdx.x;
    if (t < 512) v[t] = (t < 256) ? z_ph[t] : init_ph[t - 256];
    if (t < 64) out_zero[t] = 0.f;
    __syncthreads();
    {   // layer0: 256 rows, K=512, 4-way k-split
        int row = t & 255, part = t >> 8;
        const float* w = W0 + (size_t)row * 512 + part * 128;
        const float* vv = v + part * 128;
        float a = 0.f;
        for (int k = 0; k < 128; ++k) a += w[k] * vv[k];
        red[part][row] = a;
    }
    __syncthreads();
    if (t < 256) {
        float a = b0[t] + red[0][t] + red[1][t] + red[2][t] + red[3][t];
        h0[t] = fmaxf(a, 0.f);
    }
    __syncthreads();
    {   // layer1: 128 rows, K=256, 8-way k-split
        int row = t & 127, part = t >> 7;
        const float* w = W1 + (size_t)row * 256 + part * 32;
        const float* vv = h0 + part * 32;
        float a = 0.f;
        for (int k = 0; k < 32; ++k) a += w[k] * vv[k];
        red1[part][row] = a;
    }
    __syncthreads();
    if (t < 128) {
        float a = b1[t];
        for (int p = 0; p < 8; ++p) a += red1[p][t];
        h1[t] = fmaxf(a, 0.f);
    }
    __syncthreads();
    {   // layer2: 256 rows, K=128, 4-way k-split
        int row = t & 255, part = t >> 8;
        const float* w = W2 + (size_t)row * 128 + part * 32;
        const float* vv = h1 + part * 32;
        float a = 0.f;
        for (int k = 0; k < 32; ++k) a += w[k] * vv[k];
        red[part][row] = a;
    }
    __syncthreads();
    if (t < 256) c0_out[t] = b2[t] + red[0][t] + red[1][t] + red[2][t] + red[3][t];
}

// ---------------------------------------------------------------------------
// K2: generic C[m,n] = act( dot(Arow(m), W[n, woff:woff+K]) + bias[n] )
// mode 0: Arow = A + m*K
// mode 1: Arow = x-row ((m/127)*128 + m%127 + 1)   (skips node 0 per sample)
// mode 2: Arow = (m%127==0) ? c0 : A + (m-1)*K     (content_seq)
// grid (M/16, N/256), block 256, dyn LDS = 16*K floats
// ---------------------------------------------------------------------------
__global__ __launch_bounds__(256) void gemm_rows(
    const float* __restrict__ A, const float* __restrict__ W,
    const float* __restrict__ bias, const float* __restrict__ c0,
    float* __restrict__ C, int M, int N, int K,
    int ldw, int woff, int mode, int act)
{
    extern __shared__ float As[];
    const int tid = threadIdx.x;
    const int m0 = blockIdx.x * 16;
    const int tot = 16 * K;
    for (int idx = tid; idx < tot; idx += 256) {
        int r = idx / K, k = idx - r * K;
        int m = m0 + r;
        const float* Ar;
        if (mode == 1) {
            int ss = m / 127; int tt = m - ss * 127;
            Ar = A + (size_t)(ss * 128 + tt + 1) * K;
        } else if (mode == 2) {
            Ar = ((m % 127) == 0) ? c0 : (A + (size_t)(m - 1) * K);
        } else {
            Ar = A + (size_t)m * K;
        }
        As[idx] = Ar[k];
    }
    __syncthreads();
    const int n = blockIdx.y * 256 + tid;
    float acc[16];
    const float bv = bias ? bias[n] : 0.f;
#pragma unroll
    for (int r = 0; r < 16; ++r) acc[r] = bv;
    const float* Wp = W + (size_t)n * ldw + woff;
    const int K4 = K >> 2;
    for (int k4 = 0; k4 < K4; ++k4) {
        const float4 w = ((const float4*)Wp)[k4];
#pragma unroll
        for (int r = 0; r < 16; ++r) {
            const float4 a = *(const float4*)&As[r * K + k4 * 4];
            acc[r] += a.x * w.x + a.y * w.y + a.z * w.z + a.w * w.w;
        }
    }
#pragma unroll
    for (int r = 0; r < 16; ++r) {
        float vv = act ? fmaxf(acc[r], 0.f) : acc[r];
        C[(size_t)(m0 + r) * N + n] = vv;
    }
}

// ---------------------------------------------------------------------------
// K3: GRU scan, one workgroup per sample. gi = precomputed x_t@Wih.T + bih.
// ---------------------------------------------------------------------------
__global__ __launch_bounds__(256) void gru_scan(
    const float* __restrict__ gi, const float* __restrict__ Whh,
    const float* __restrict__ bhh, float* __restrict__ outp, int T)
{
    const int s = blockIdx.x, j = threadIdx.x;
    __shared__ float hs[256];
    hs[j] = 0.f;
    const float br = bhh[j], bz = bhh[256 + j], bn = bhh[512 + j];
    const float4* Wr = (const float4*)(Whh + (size_t)j * 256);
    const float4* Wz = (const float4*)(Whh + (size_t)(256 + j) * 256);
    const float4* Wn = (const float4*)(Whh + (size_t)(512 + j) * 256);
    const float* g0 = gi + (size_t)s * T * G_;
    float* o0 = outp + (size_t)s * T * D_;
    __syncthreads();
    for (int t = 0; t < T; ++t) {
        float ar = br, az = bz, an = bn;
        const float4* h4p = (const float4*)hs;
#pragma unroll 4
        for (int k4 = 0; k4 < 64; ++k4) {
            const float4 h4 = h4p[k4];
            const float4 wr = Wr[k4], wz = Wz[k4], wn = Wn[k4];
            ar += h4.x * wr.x + h4.y * wr.y + h4.z * wr.z + h4.w * wr.w;
            az += h4.x * wz.x + h4.y * wz.y + h4.z * wz.z + h4.w * wz.w;
            an += h4.x * wn.x + h4.y * wn.y + h4.z * wn.z + h4.w * wn.w;
        }
        const float* g = g0 + (size_t)t * G_;
        const float r = sigmoidf_(g[j] + ar);
        const float z = sigmoidf_(g[256 + j] + az);
        const float n = tanhf(g[512 + j] + r * an);
        const float hj = hs[j];
        const float hnew = (1.f - z) * n + z * hj;
        __syncthreads();
        hs[j] = hnew;
        o0[(size_t)t * D_ + j] = hnew;
        __syncthreads();
    }
}

// ---------------------------------------------------------------------------
// K4: float -> bf16 conversion (for W1)
// ---------------------------------------------------------------------------
__global__ __launch_bounds__(256) void cvt_bf16(const float* __restrict__ src,
                                                unsigned short* __restrict__ dst, int n)
{
    int i = blockIdx.x * 256 + threadIdx.x;
    if (i < n) dst[i] = f2bf(src[i]);
}

// ---------------------------------------------------------------------------
// K5: fused edge readout. Block = (64 edges of sample s).
// h1[e] = relu(A[s,j(e)] + B[s,i(e)]) (bf16, LDS) ; h2 = relu(h1@W1.T + b1)
// via MFMA 16x16x32_bf16 ; logits = h2@W2.T + b2 ; softmax ; BCE ; sum.
// ---------------------------------------------------------------------------
#define LDP 264   // 256 + 8 bf16 pad (16B) to break bank aliasing

__global__ __launch_bounds__(256) void edge_kernel(
    const float* __restrict__ Amat, const float* __restrict__ Bmat,
    const unsigned short* __restrict__ w1bf, const float* __restrict__ b1,
    const float* __restrict__ W2, const float* __restrict__ b2,
    const float* __restrict__ con, float* __restrict__ out)
{
    __shared__ __align__(16) unsigned short h1s[64 * LDP];
    __shared__ int ijs[128];
    __shared__ float redw[4][2];
    const int tid = threadIdx.x;
    const int s = blockIdx.y;
    const int e0 = blockIdx.x * 64;

    if (tid < 64) {
        int e = e0 + tid;
        int i = (int)((sqrtf(8.f * (float)e + 1.f) - 1.f) * 0.5f);
        while (((i + 1) * (i + 2)) / 2 <= e) ++i;
        while ((i * (i + 1)) / 2 > e) --i;
        ijs[tid * 2] = i;
        ijs[tid * 2 + 1] = e - (i * (i + 1)) / 2;
    }
    __syncthreads();

    // build h1 tile: 64 edges x 256 k, bf16
    for (int idx = tid; idx < 64 * 64; idx += 256) {
        int e = idx >> 6, k4 = idx & 63;
        int i = ijs[e * 2], j = ijs[e * 2 + 1];
        float4 a = ((const float4*)(Amat + ((size_t)s * NM1 + j) * D_))[k4];
        float4 b = ((const float4*)(Bmat + ((size_t)s * NM1 + i) * D_))[k4];
        float4 h;
        h.x = fmaxf(a.x + b.x, 0.f);
        h.y = fmaxf(a.y + b.y, 0.f);
        h.z = fmaxf(a.z + b.z, 0.f);
        h.w = fmaxf(a.w + b.w, 0.f);
        store4bf(&h1s[e * LDP + k4 * 4], h);
    }
    __syncthreads();

    const int wave = tid >> 6, lane = tid & 63;
    const int lr = lane & 15, quad = lane >> 4;

    v4f acc[8];
    const v4f vzero = {0.f, 0.f, 0.f, 0.f};
#pragma unroll
    for (int nt = 0; nt < 8; ++nt) acc[nt] = vzero;

#pragma unroll
    for (int kt = 0; kt < 8; ++kt) {
        const int ko = kt * 32 + quad * 8;
        const v8bf afrag = *reinterpret_cast<const v8bf*>(&h1s[(wave * 16 + lr) * LDP + ko]);
#pragma unroll
        for (int nt = 0; nt < 8; ++nt) {
            const v8bf bfrag = *reinterpret_cast<const v8bf*>(&w1bf[(size_t)(nt * 16 + lr) * D_ + ko]);
            acc[nt] = __builtin_amdgcn_mfma_f32_16x16x32_bf16(afrag, bfrag, acc[nt], 0, 0, 0);
        }
    }

    // epilogue: relu(+b1), x W2 (128->2), reduce over oc lanes, softmax+BCE
    float w20[8], w21[8], b1v[8];
#pragma unroll
    for (int nt = 0; nt < 8; ++nt) {
        int oc = nt * 16 + lr;
        w20[nt] = W2[oc];
        w21[nt] = W2[128 + oc];
        b1v[nt] = b1[oc];
    }
    const float cb20 = b2[0], cb21 = b2[1];
    float bsum0 = 0.f, bsum1 = 0.f;
#pragma unroll
    for (int r = 0; r < 4; ++r) {
        float l0 = 0.f, l1 = 0.f;
#pragma unroll
        for (int nt = 0; nt < 8; ++nt) {
            float h2 = fmaxf(acc[nt][r] + b1v[nt], 0.f);
            l0 += h2 * w20[nt];
            l1 += h2 * w21[nt];
        }
#pragma unroll
        for (int d = 1; d < 16; d <<= 1) {
            l0 += __shfl_xor(l0, d);
            l1 += __shfl_xor(l1, d);
        }
        if (lr == 0) {
            int e = e0 + wave * 16 + quad * 4 + r;
            l0 += cb20; l1 += cb21;
            float mx = fmaxf(l0, l1);
            float lse = mx + logf(__expf(l0 - mx) + __expf(l1 - mx));
            float lp0 = fmaxf(l0 - lse, -100.f);
            float lp1 = fmaxf(l1 - lse, -100.f);
            float c0v = con[((size_t)s * TRI_ + e) * 2];
            float c1v = con[((size_t)s * TRI_ + e) * 2 + 1];
            bsum0 -= c0v * lp0 + (1.f - c0v) * lp1;
            bsum1 -= c1v * lp1 + (1.f - c1v) * lp0;
        }
    }
#pragma unroll
    for (int d = 1; d < 64; d <<= 1) {
        bsum0 += __shfl_xor(bsum0, d);
        bsum1 += __shfl_xor(bsum1, d);
    }
    if (lane == 0) { redw[wave][0] = bsum0; redw[wave][1] = bsum1; }
    __syncthreads();
    if (tid == 0) {
        float t0 = redw[0][0] + redw[1][0] + redw[2][0] + redw[3][0];
        float t1 = redw[0][1] + redw[1][1] + redw[2][1] + redw[3][1];
        atomicAdd(&out[s * 2], t0);
        atomicAdd(&out[s * 2 + 1], t1);
    }
}

// ---------------------------------------------------------------------------
extern "C" void kernel_launch(void* const* d_in, const int* in_sizes, int n_in,
                              void* d_out, int out_size, void* d_ws, size_t ws_size,
                              hipStream_t stream)
{
    (void)in_sizes; (void)n_in; (void)out_size; (void)ws_size;
    const float* x        = (const float*)d_in[0];
    const float* con      = (const float*)d_in[1];
    const float* z_ph     = (const float*)d_in[2];
    const float* init_ph  = (const float*)d_in[3];
    const float* cc_W0    = (const float*)d_in[4];
    const float* cc_b0    = (const float*)d_in[5];
    const float* cc_W1    = (const float*)d_in[6];
    const float* cc_b1    = (const float*)d_in[7];
    const float* cc_W2    = (const float*)d_in[8];
    const float* cc_b2    = (const float*)d_in[9];
    const float* er_W0    = (const float*)d_in[10];
    const float* er_b0    = (const float*)d_in[11];
    const float* er_W1    = (const float*)d_in[12];
    const float* er_b1    = (const float*)d_in[13];
    const float* er_W2    = (const float*)d_in[14];
    const float* er_b2    = (const float*)d_in[15];
    const float* rr_W     = (const float*)d_in[16];
    const float* rr_b     = (const float*)d_in[17];
    const float* dec_Wih  = (const float*)d_in[18];
    const float* dec_Whh  = (const float*)d_in[19];
    const float* dec_bih  = (const float*)d_in[20];
    const float* dec_bhh  = (const float*)d_in[21];
    const float* upd_Wih  = (const float*)d_in[22];
    const float* upd_Whh  = (const float*)d_in[23];
    const float* upd_bih  = (const float*)d_in[24];
    const float* upd_bhh  = (const float*)d_in[25];
    float* out = (float*)d_out;

    float* ws = (float*)d_ws;
    float* c0v  = ws;                               // 256
    float* gi   = ws + 256;                         // M_*G_ (gi_u, then gi_d)
    float* bufA = gi + (size_t)M_ * G_;             // M_*D_ (rnninp, then Amat)
    float* bufB = bufA + (size_t)M_ * D_;           // M_*D_ (u_out, then Bmat)
    float* memb = bufB + (size_t)M_ * D_;           // M_*D_ (mem)
    unsigned short* w1bf = (unsigned short*)(memb + (size_t)M_ * D_); // 128*256

    // 1) c0 + zero out
    c0_kernel<<<1, 1024, 0, stream>>>(z_ph, init_ph, cc_W0, cc_b0, cc_W1, cc_b1,
                                      cc_W2, cc_b2, c0v, out);
    // 2) rnninp = relu(x[:,1:] @ rr_W.T + rr_b)   -> bufA
    gemm_rows<<<dim3(M_ / 16, 1), 256, 16 * F_ * 4, stream>>>(
        x, rr_W, rr_b, nullptr, bufA, M_, D_, F_, F_, 0, 1, 1);
    // 3) gi_u = rnninp @ upd_Wih.T + upd_bih      -> gi
    gemm_rows<<<dim3(M_ / 16, 3), 256, 16 * D_ * 4, stream>>>(
        bufA, upd_Wih, upd_bih, nullptr, gi, M_, G_, D_, D_, 0, 0, 0);
    // 4) u_out = GRU(gi_u; upd)                   -> bufB
    gru_scan<<<S_, 256, 0, stream>>>(gi, upd_Whh, upd_bhh, bufB, NM1);
    // 5) gi_d = content_seq @ dec_Wih.T + dec_bih -> gi
    gemm_rows<<<dim3(M_ / 16, 3), 256, 16 * D_ * 4, stream>>>(
        bufB, dec_Wih, dec_bih, c0v, gi, M_, G_, D_, D_, 0, 2, 0);
    // 6) mem = GRU(gi_d; dec)                     -> memb
    gru_scan<<<S_, 256, 0, stream>>>(gi, dec_Whh, dec_bhh, memb, NM1);
    // 7) Amat = mem @ er_W0[:, :256].T            -> bufA
    gemm_rows<<<dim3(M_ / 16, 1), 256, 16 * D_ * 4, stream>>>(
        memb, er_W0, nullptr, nullptr, bufA, M_, D_, D_, 512, 0, 0, 0);
    // 8) Bmat = mem @ er_W0[:, 256:].T + er_b0    -> bufB
    gemm_rows<<<dim3(M_ / 16, 1), 256, 16 * D_ * 4, stream>>>(
        memb, er_W0, er_b0, nullptr, bufB, M_, D_, D_, 512, 256, 0, 0);
    // 9) W1 -> bf16
    cvt_bf16<<<(128 * 256) / 256, 256, 0, stream>>>(er_W1, w1bf, 128 * 256);
    // 10) fused edge readout -> out (atomicAdd)
    edge_kernel<<<dim3(TRI_ / 64, S_), 256, 0, stream>>>(
        bufA, bufB, w1bf, er_b1, er_W2, er_b2, con, out);
}

// Round 2
// 880.368 us; speedup vs baseline: 7.1220x; 7.1220x over previous
//
#include <hip/hip_runtime.h>
#include <cstddef>

#define S_ 32
#define NM1 127
#define D_ 256
#define F_ 516
#define TRI_ 8128
#define G_ 768
#define M_ (S_ * NM1)   // 4064

typedef __bf16 v8bf __attribute__((ext_vector_type(8)));
typedef __bf16 bf2 __attribute__((ext_vector_type(2)));
typedef float v4f __attribute__((ext_vector_type(4)));

#if __has_builtin(__builtin_amdgcn_fdot2_f32_bf16)
#define HAS_DOT2 1
#else
#define HAS_DOT2 0
#endif

__device__ __forceinline__ unsigned short f2bf(float f) {
    unsigned int u = __float_as_uint(f);
    unsigned int r = (u + 0x7FFFu + ((u >> 16) & 1u)) >> 16;
    return (unsigned short)r;
}

__device__ __forceinline__ void store4bf(unsigned short* p, float4 v) {
    ushort4 q;
    q.x = f2bf(v.x); q.y = f2bf(v.y); q.z = f2bf(v.z); q.w = f2bf(v.w);
    *(ushort4*)p = q;
}

__device__ __forceinline__ bf2 u2bf2(unsigned int u) {
    union { unsigned int u; bf2 v; } x; x.u = u; return x.v;
}

__device__ __forceinline__ float bflo(unsigned int u) { return __uint_as_float(u << 16); }
__device__ __forceinline__ float bfhi(unsigned int u) { return __uint_as_float(u & 0xffff0000u); }

__device__ __forceinline__ float sigmoidf_(float x) { return 1.f / (1.f + __expf(-x)); }

// ---------------------------------------------------------------------------
// K1: c0 = MLPReadout([z;init]) through cc_*; also zero d_out. 1 block x 1024.
// ---------------------------------------------------------------------------
__global__ __launch_bounds__(1024) void c0_kernel(
    const float* __restrict__ z_ph, const float* __restrict__ init_ph,
    const float* __restrict__ W0, const float* __restrict__ b0,
    const float* __restrict__ W1, const float* __restrict__ b1,
    const float* __restrict__ W2, const float* __restrict__ b2,
    float* __restrict__ c0_out, float* __restrict__ out_zero)
{
    __shared__ float v[512];
    __shared__ float h0[256];
    __shared__ float h1[128];
    __shared__ float red[4][256];
    __shared__ float red1[8][128];
    const int t = threadIdx.x;
    if (t < 512) v[t] = (t < 256) ? z_ph[t] : init_ph[t - 256];
    if (t < 64) out_zero[t] = 0.f;
    __syncthreads();
    {
        int row = t & 255, part = t >> 8;
        const float* w = W0 + (size_t)row * 512 + part * 128;
        const float* vv = v + part * 128;
        float a = 0.f;
        for (int k = 0; k < 128; ++k) a += w[k] * vv[k];
        red[part][row] = a;
    }
    __syncthreads();
    if (t < 256) {
        float a = b0[t] + red[0][t] + red[1][t] + red[2][t] + red[3][t];
        h0[t] = fmaxf(a, 0.f);
    }
    __syncthreads();
    {
        int row = t & 127, part = t >> 7;
        const float* w = W1 + (size_t)row * 256 + part * 32;
        const float* vv = h0 + part * 32;
        float a = 0.f;
        for (int k = 0; k < 32; ++k) a += w[k] * vv[k];
        red1[part][row] = a;
    }
    __syncthreads();
    if (t < 128) {
        float a = b1[t];
        for (int p = 0; p < 8; ++p) a += red1[p][t];
        h1[t] = fmaxf(a, 0.f);
    }
    __syncthreads();
    {
        int row = t & 255, part = t >> 8;
        const float* w = W2 + (size_t)row * 128 + part * 32;
        const float* vv = h1 + part * 32;
        float a = 0.f;
        for (int k = 0; k < 32; ++k) a += w[k] * vv[k];
        red[part][row] = a;
    }
    __syncthreads();
    if (t < 256) c0_out[t] = b2[t] + red[0][t] + red[1][t] + red[2][t] + red[3][t];
}

// ---------------------------------------------------------------------------
// K2: generic row GEMM (fp32) — unchanged from R1.
// ---------------------------------------------------------------------------
__global__ __launch_bounds__(256) void gemm_rows(
    const float* __restrict__ A, const float* __restrict__ W,
    const float* __restrict__ bias, const float* __restrict__ c0,
    float* __restrict__ C, int M, int N, int K,
    int ldw, int woff, int mode, int act)
{
    extern __shared__ float As[];
    const int tid = threadIdx.x;
    const int m0 = blockIdx.x * 16;
    const int tot = 16 * K;
    for (int idx = tid; idx < tot; idx += 256) {
        int r = idx / K, k = idx - r * K;
        int m = m0 + r;
        const float* Ar;
        if (mode == 1) {
            int ss = m / 127; int tt = m - ss * 127;
            Ar = A + (size_t)(ss * 128 + tt + 1) * K;
        } else if (mode == 2) {
            Ar = ((m % 127) == 0) ? c0 : (A + (size_t)(m - 1) * K);
        } else {
            Ar = A + (size_t)m * K;
        }
        As[idx] = Ar[k];
    }
    __syncthreads();
    const int n = blockIdx.y * 256 + tid;
    float acc[16];
    const float bv = bias ? bias[n] : 0.f;
#pragma unroll
    for (int r = 0; r < 16; ++r) acc[r] = bv;
    const float* Wp = W + (size_t)n * ldw + woff;
    const int K4 = K >> 2;
    for (int k4 = 0; k4 < K4; ++k4) {
        const float4 w = ((const float4*)Wp)[k4];
#pragma unroll
        for (int r = 0; r < 16; ++r) {
            const float4 a = *(const float4*)&As[r * K + k4 * 4];
            acc[r] += a.x * w.x + a.y * w.y + a.z * w.z + a.w * w.w;
        }
    }
#pragma unroll
    for (int r = 0; r < 16; ++r) {
        float vv = act ? fmaxf(acc[r], 0.f) : acc[r];
        C[(size_t)(m0 + r) * N + n] = vv;
    }
}

// ---------------------------------------------------------------------------
// K2b: pack Whh (768x256 f32) -> wpT (128x768 u32), wpT[p][j] =
//      pack(bf16(Whh[j][2p]) , bf16(Whh[j][2p+1]))
// ---------------------------------------------------------------------------
__global__ __launch_bounds__(256) void pack_whh(const float* __restrict__ W,
                                                unsigned int* __restrict__ wpT)
{
    int idx = blockIdx.x * 256 + threadIdx.x;
    if (idx >= 128 * 768) return;
    int p = idx / 768, j = idx - p * 768;
    float a = W[(size_t)j * 256 + 2 * p];
    float b = W[(size_t)j * 256 + 2 * p + 1];
    wpT[idx] = (unsigned int)f2bf(a) | ((unsigned int)f2bf(b) << 16);
}

// ---------------------------------------------------------------------------
// K3: GRU scan v2. One block (768 threads) per sample. Whh register-resident
// (bf16 pairs, 128 VGPRs/thread). Thread j computes dot(h, Whh_row_j) via
// v_dot2_f32_bf16 against packed-bf16 h broadcast from LDS. Recurrence fp32.
// ---------------------------------------------------------------------------
__global__ __launch_bounds__(768, 3) void gru_scan2(
    const float* __restrict__ gi, const unsigned int* __restrict__ wpT,
    const float* __restrict__ bhh, float* __restrict__ outp, int T)
{
    const int s = blockIdx.x, j = threadIdx.x;
    __shared__ unsigned int hb[128];   // packed bf16 pairs of h
    __shared__ float hs[256];          // fp32 h (recurrence + fallback)
    __shared__ float dred[768];        // per-row dot results

    unsigned int w[128];
#pragma unroll
    for (int p = 0; p < 128; ++p) w[p] = wpT[(size_t)p * 768 + j];

    float br = 0.f, bz = 0.f, bn = 0.f;
    float g_r = 0.f, g_z = 0.f, g_n = 0.f;
    const float* g0 = gi + (size_t)s * T * G_;
    float* o0 = outp + (size_t)s * T * D_;
    if (j < 256) {
        br = bhh[j]; bz = bhh[256 + j]; bn = bhh[512 + j];
        g_r = g0[j]; g_z = g0[256 + j]; g_n = g0[512 + j];
        hs[j] = 0.f;
    }
    if (j < 128) hb[j] = 0u;
    __syncthreads();

    for (int t = 0; t < T; ++t) {
        float a0 = 0.f, a1 = 0.f, a2 = 0.f, a3 = 0.f;
#if HAS_DOT2
        const uint4* hb4 = (const uint4*)hb;
#pragma unroll
        for (int p4 = 0; p4 < 32; ++p4) {
            const uint4 hq = hb4[p4];   // LDS broadcast
            a0 = __builtin_amdgcn_fdot2_f32_bf16(u2bf2(w[4 * p4 + 0]), u2bf2(hq.x), a0, false);
            a1 = __builtin_amdgcn_fdot2_f32_bf16(u2bf2(w[4 * p4 + 1]), u2bf2(hq.y), a1, false);
            a2 = __builtin_amdgcn_fdot2_f32_bf16(u2bf2(w[4 * p4 + 2]), u2bf2(hq.z), a2, false);
            a3 = __builtin_amdgcn_fdot2_f32_bf16(u2bf2(w[4 * p4 + 3]), u2bf2(hq.w), a3, false);
        }
#else
        const float4* h4 = (const float4*)hs;
#pragma unroll
        for (int p4 = 0; p4 < 32; ++p4) {
            const float4 hva = h4[2 * p4], hvb = h4[2 * p4 + 1];
            const unsigned int wa = w[4 * p4 + 0], wb = w[4 * p4 + 1];
            const unsigned int wc = w[4 * p4 + 2], wd = w[4 * p4 + 3];
            a0 += bflo(wa) * hva.x + bfhi(wa) * hva.y;
            a1 += bflo(wb) * hva.z + bfhi(wb) * hva.w;
            a2 += bflo(wc) * hvb.x + bfhi(wc) * hvb.y;
            a3 += bflo(wd) * hvb.z + bfhi(wd) * hvb.w;
        }
#endif
        dred[j] = (a0 + a1) + (a2 + a3);
        __syncthreads();

        if (j < 256) {
            float ng_r = 0.f, ng_z = 0.f, ng_n = 0.f;
            if (t + 1 < T) {
                const float* gn = g0 + (size_t)(t + 1) * G_;
                ng_r = gn[j]; ng_z = gn[256 + j]; ng_n = gn[512 + j];
            }
            const float r = sigmoidf_(g_r + dred[j] + br);
            const float z = sigmoidf_(g_z + dred[256 + j] + bz);
            const float n = tanhf(g_n + r * (dred[512 + j] + bn));
            const float hj = hs[j];
            const float hnew = (1.f - z) * n + z * hj;
            hs[j] = hnew;
            o0[(size_t)t * D_ + j] = hnew;
            const float hoth = __shfl_xor(hnew, 1);
            if ((j & 1) == 0) {
                hb[j >> 1] = (unsigned int)f2bf(hnew) | ((unsigned int)f2bf(hoth) << 16);
            }
            g_r = ng_r; g_z = ng_z; g_n = ng_n;
        }
        __syncthreads();
    }
}

// ---------------------------------------------------------------------------
// K4: float -> bf16 conversion (for W1)
// ---------------------------------------------------------------------------
__global__ __launch_bounds__(256) void cvt_bf16(const float* __restrict__ src,
                                                unsigned short* __restrict__ dst, int n)
{
    int i = blockIdx.x * 256 + threadIdx.x;
    if (i < n) dst[i] = f2bf(src[i]);
}

// ---------------------------------------------------------------------------
// K5: fused edge readout. 64 edges/block. h1 tile in LDS with 16B-block XOR
// swizzle (pc = (k/8) ^ (e&7)) -> 2 lanes/bank on MFMA A-frag reads (free).
// ---------------------------------------------------------------------------
__global__ __launch_bounds__(256) void edge_kernel(
    const float* __restrict__ Amat, const float* __restrict__ Bmat,
    const unsigned short* __restrict__ w1bf, const float* __restrict__ b1,
    const float* __restrict__ W2, const float* __restrict__ b2,
    const float* __restrict__ con, float* __restrict__ out)
{
    __shared__ __align__(16) unsigned short h1s[64 * 256];
    __shared__ int ijs[128];
    __shared__ float redw[4][2];
    const int tid = threadIdx.x;
    const int s = blockIdx.y;
    const int e0 = blockIdx.x * 64;

    if (tid < 64) {
        int e = e0 + tid;
        int i = (int)((sqrtf(8.f * (float)e + 1.f) - 1.f) * 0.5f);
        while (((i + 1) * (i + 2)) / 2 <= e) ++i;
        while ((i * (i + 1)) / 2 > e) --i;
        ijs[tid * 2] = i;
        ijs[tid * 2 + 1] = e - (i * (i + 1)) / 2;
    }
    __syncthreads();

    for (int idx = tid; idx < 64 * 64; idx += 256) {
        int e = idx >> 6, k4 = idx & 63;
        int i = ijs[e * 2], j = ijs[e * 2 + 1];
        float4 a = ((const float4*)(Amat + ((size_t)s * NM1 + j) * D_))[k4];
        float4 b = ((const float4*)(Bmat + ((size_t)s * NM1 + i) * D_))[k4];
        float4 h;
        h.x = fmaxf(a.x + b.x, 0.f);
        h.y = fmaxf(a.y + b.y, 0.f);
        h.z = fmaxf(a.z + b.z, 0.f);
        h.w = fmaxf(a.w + b.w, 0.f);
        int pc = (k4 >> 1) ^ (e & 7);
        store4bf(&h1s[e * 256 + (pc << 3) + ((k4 & 1) << 2)], h);
    }
    __syncthreads();

    const int wave = tid >> 6, lane = tid & 63;
    const int lr = lane & 15, quad = lane >> 4;
    const int row = wave * 16 + lr;

    v4f acc[8];
    const v4f vzero = {0.f, 0.f, 0.f, 0.f};
#pragma unroll
    for (int nt = 0; nt < 8; ++nt) acc[nt] = vzero;

#pragma unroll
    for (int kt = 0; kt < 8; ++kt) {
        const int c = kt * 4 + quad;
        const int pc = c ^ (row & 7);
        const v8bf afrag = *reinterpret_cast<const v8bf*>(&h1s[row * 256 + (pc << 3)]);
        const int ko = kt * 32 + quad * 8;
#pragma unroll
        for (int nt = 0; nt < 8; ++nt) {
            const v8bf bfrag = *reinterpret_cast<const v8bf*>(&w1bf[(size_t)(nt * 16 + lr) * D_ + ko]);
            acc[nt] = __builtin_amdgcn_mfma_f32_16x16x32_bf16(afrag, bfrag, acc[nt], 0, 0, 0);
        }
    }

    float w20[8], w21[8], b1v[8];
#pragma unroll
    for (int nt = 0; nt < 8; ++nt) {
        int oc = nt * 16 + lr;
        w20[nt] = W2[oc];
        w21[nt] = W2[128 + oc];
        b1v[nt] = b1[oc];
    }
    const float cb20 = b2[0], cb21 = b2[1];
    float bsum0 = 0.f, bsum1 = 0.f;
#pragma unroll
    for (int r = 0; r < 4; ++r) {
        float l0 = 0.f, l1 = 0.f;
#pragma unroll
        for (int nt = 0; nt < 8; ++nt) {
            float h2 = fmaxf(acc[nt][r] + b1v[nt], 0.f);
            l0 += h2 * w20[nt];
            l1 += h2 * w21[nt];
        }
#pragma unroll
        for (int d = 1; d < 16; d <<= 1) {
            l0 += __shfl_xor(l0, d);
            l1 += __shfl_xor(l1, d);
        }
        if (lr == 0) {
            int e = e0 + wave * 16 + quad * 4 + r;
            l0 += cb20; l1 += cb21;
            float mx = fmaxf(l0, l1);
            float lse = mx + logf(__expf(l0 - mx) + __expf(l1 - mx));
            float lp0 = fmaxf(l0 - lse, -100.f);
            float lp1 = fmaxf(l1 - lse, -100.f);
            float c0v = con[((size_t)s * TRI_ + e) * 2];
            float c1v = con[((size_t)s * TRI_ + e) * 2 + 1];
            bsum0 -= c0v * lp0 + (1.f - c0v) * lp1;
            bsum1 -= c1v * lp1 + (1.f - c1v) * lp0;
        }
    }
#pragma unroll
    for (int d = 1; d < 64; d <<= 1) {
        bsum0 += __shfl_xor(bsum0, d);
        bsum1 += __shfl_xor(bsum1, d);
    }
    if (lane == 0) { redw[wave][0] = bsum0; redw[wave][1] = bsum1; }
    __syncthreads();
    if (tid == 0) {
        float t0 = redw[0][0] + redw[1][0] + redw[2][0] + redw[3][0];
        float t1 = redw[0][1] + redw[1][1] + redw[2][1] + redw[3][1];
        atomicAdd(&out[s * 2], t0);
        atomicAdd(&out[s * 2 + 1], t1);
    }
}

// ---------------------------------------------------------------------------
extern "C" void kernel_launch(void* const* d_in, const int* in_sizes, int n_in,
                              void* d_out, int out_size, void* d_ws, size_t ws_size,
                              hipStream_t stream)
{
    (void)in_sizes; (void)n_in; (void)out_size; (void)ws_size;
    const float* x        = (const float*)d_in[0];
    const float* con      = (const float*)d_in[1];
    const float* z_ph     = (const float*)d_in[2];
    const float* init_ph  = (const float*)d_in[3];
    const float* cc_W0    = (const float*)d_in[4];
    const float* cc_b0    = (const float*)d_in[5];
    const float* cc_W1    = (const float*)d_in[6];
    const float* cc_b1    = (const float*)d_in[7];
    const float* cc_W2    = (const float*)d_in[8];
    const float* cc_b2    = (const float*)d_in[9];
    const float* er_W0    = (const float*)d_in[10];
    const float* er_b0    = (const float*)d_in[11];
    const float* er_W1    = (const float*)d_in[12];
    const float* er_b1    = (const float*)d_in[13];
    const float* er_W2    = (const float*)d_in[14];
    const float* er_b2    = (const float*)d_in[15];
    const float* rr_W     = (const float*)d_in[16];
    const float* rr_b     = (const float*)d_in[17];
    const float* dec_Wih  = (const float*)d_in[18];
    const float* dec_Whh  = (const float*)d_in[19];
    const float* dec_bih  = (const float*)d_in[20];
    const float* dec_bhh  = (const float*)d_in[21];
    const float* upd_Wih  = (const float*)d_in[22];
    const float* upd_Whh  = (const float*)d_in[23];
    const float* upd_bih  = (const float*)d_in[24];
    const float* upd_bhh  = (const float*)d_in[25];
    float* out = (float*)d_out;

    float* ws = (float*)d_ws;
    float* c0v  = ws;                               // 256
    float* gi   = ws + 256;                         // M_*G_
    float* bufA = gi + (size_t)M_ * G_;             // M_*D_ (rnninp, Amat)
    float* bufB = bufA + (size_t)M_ * D_;           // M_*D_ (u_out, Bmat)
    float* memb = bufB + (size_t)M_ * D_;           // M_*D_ (mem)
    unsigned short* w1bf = (unsigned short*)(memb + (size_t)M_ * D_); // 128*256
    unsigned int* wpU = (unsigned int*)(w1bf + 128 * 256);            // 128*768
    unsigned int* wpD = wpU + 128 * 768;                              // 128*768

    // 1) c0 + zero out; weight prep
    c0_kernel<<<1, 1024, 0, stream>>>(z_ph, init_ph, cc_W0, cc_b0, cc_W1, cc_b1,
                                      cc_W2, cc_b2, c0v, out);
    pack_whh<<<(128 * 768 + 255) / 256, 256, 0, stream>>>(upd_Whh, wpU);
    pack_whh<<<(128 * 768 + 255) / 256, 256, 0, stream>>>(dec_Whh, wpD);
    cvt_bf16<<<(128 * 256) / 256, 256, 0, stream>>>(er_W1, w1bf, 128 * 256);
    // 2) rnninp = relu(x[:,1:] @ rr_W.T + rr_b)   -> bufA
    gemm_rows<<<dim3(M_ / 16, 1), 256, 16 * F_ * 4, stream>>>(
        x, rr_W, rr_b, nullptr, bufA, M_, D_, F_, F_, 0, 1, 1);
    // 3) gi_u = rnninp @ upd_Wih.T + upd_bih      -> gi
    gemm_rows<<<dim3(M_ / 16, 3), 256, 16 * D_ * 4, stream>>>(
        bufA, upd_Wih, upd_bih, nullptr, gi, M_, G_, D_, D_, 0, 0, 0);
    // 4) u_out = GRU(gi_u; upd)                   -> bufB
    gru_scan2<<<S_, 768, 0, stream>>>(gi, wpU, upd_bhh, bufB, NM1);
    // 5) gi_d = content_seq @ dec_Wih.T + dec_bih -> gi
    gemm_rows<<<dim3(M_ / 16, 3), 256, 16 * D_ * 4, stream>>>(
        bufB, dec_Wih, dec_bih, c0v, gi, M_, G_, D_, D_, 0, 2, 0);
    // 6) mem = GRU(gi_d; dec)                     -> memb
    gru_scan2<<<S_, 768, 0, stream>>>(gi, wpD, dec_bhh, memb, NM1);
    // 7) Amat = mem @ er_W0[:, :256].T            -> bufA
    gemm_rows<<<dim3(M_ / 16, 1), 256, 16 * D_ * 4, stream>>>(
        memb, er_W0, nullptr, nullptr, bufA, M_, D_, D_, 512, 0, 0, 0);
    // 8) Bmat = mem @ er_W0[:, 256:].T + er_b0    -> bufB
    gemm_rows<<<dim3(M_ / 16, 1), 256, 16 * D_ * 4, stream>>>(
        memb, er_W0, er_b0, nullptr, bufB, M_, D_, D_, 512, 256, 0, 0);
    // 9) fused edge readout -> out (atomicAdd)
    edge_kernel<<<dim3(TRI_ / 64, S_), 256, 0, stream>>>(
        bufA, bufB, w1bf, er_b1, er_W2, er_b2, con, out);
}